// Round 8
// baseline (364.087 us; speedup 1.0000x reference)
//
#include <hip/hip_runtime.h>
#include <math.h>

#define Bv   64
#define Nv   900
#define Mv   64
#define NCls 128
#define NCOLS (Nv + 1)          // 901 columns incl. dummy col 0
#define KREG 15                 // columns per lane: j = t + 64k, k=0..14
#define INFV 1000000000.0f
#define BIGV 1.0e18f            // sentinel for used/invalid slots

// uniform dynamic read (serial chain; only in the rare backtrack)
#define SEL15(arr, kidx, dst) do {            \
    int _s = arr[0];                          \
    _Pragma("unroll")                         \
    for (int _kk = 1; _kk < KREG; _kk++)      \
        _s = ((kidx) == _kk) ? arr[_kk] : _s; \
    (dst) = _s;                               \
} while (0)

// binary-tree select (depth 4) for the hot p-lookup; kidx uniform.
// HW-verified R7.
#define SELTREE15(arr, kidx, dst) do {                      \
    int _a0 = ((kidx) & 1) ? arr[1]  : arr[0];              \
    int _a1 = ((kidx) & 1) ? arr[3]  : arr[2];              \
    int _a2 = ((kidx) & 1) ? arr[5]  : arr[4];              \
    int _a3 = ((kidx) & 1) ? arr[7]  : arr[6];              \
    int _a4 = ((kidx) & 1) ? arr[9]  : arr[8];              \
    int _a5 = ((kidx) & 1) ? arr[11] : arr[10];             \
    int _a6 = ((kidx) & 1) ? arr[13] : arr[12];             \
    int _a7 = arr[14];          /* k==15 never occurs */    \
    int _b0 = ((kidx) & 2) ? _a1 : _a0;                     \
    int _b1 = ((kidx) & 2) ? _a3 : _a2;                     \
    int _b2 = ((kidx) & 2) ? _a5 : _a4;                     \
    int _b3 = ((kidx) & 2) ? _a7 : _a6;                     \
    int _c0 = ((kidx) & 4) ? _b1 : _b0;                     \
    int _c1 = ((kidx) & 4) ? _b3 : _b2;                     \
    (dst)   = ((kidx) & 8) ? _c1 : _c0;                     \
} while (0)

// uniform dynamic write (lane-targeted)
#define SET15(arr, kidx, val) do {            \
    _Pragma("unroll")                         \
    for (int _kk = 0; _kk < KREG; _kk++)      \
        if ((kidx) == _kk) arr[_kk] = (val);  \
} while (0)

// ---- wave64 reduces via DPP (rocPRIM pattern, HW-verified R4/R5/R6) --------
__device__ __forceinline__ float wave_min_f32(float x) {
#define MSTEP(ctrl, rmask)                                                \
    {                                                                     \
        int o = __builtin_amdgcn_update_dpp(__float_as_int(x),            \
                __float_as_int(x), ctrl, rmask, 0xf, false);              \
        x = fminf(x, __int_as_float(o));                                  \
    }
    MSTEP(0x111, 0xf) MSTEP(0x112, 0xf) MSTEP(0x114, 0xf) MSTEP(0x118, 0xf)
    MSTEP(0x142, 0xa) MSTEP(0x143, 0xc)
#undef MSTEP
    return __int_as_float(__builtin_amdgcn_readlane(__float_as_int(x), 63));
}

__device__ __forceinline__ unsigned wave_min_u32(unsigned x) {
#define USTEP(ctrl, rmask)                                                \
    {                                                                     \
        unsigned o = (unsigned)__builtin_amdgcn_update_dpp((int)x,        \
                     (int)x, ctrl, rmask, 0xf, false);                    \
        x = (o < x) ? o : x;                                              \
    }
    USTEP(0x111, 0xf) USTEP(0x112, 0xf) USTEP(0x114, 0xf) USTEP(0x118, 0xf)
    USTEP(0x142, 0xa) USTEP(0x143, 0xc)
#undef USTEP
    return (unsigned)__builtin_amdgcn_readlane((int)x, 63);
}

__device__ __forceinline__ float wave_sum_f32(float x) {
#define SSTEP(ctrl, rmask)                                                \
    {                                                                     \
        int o = __builtin_amdgcn_update_dpp(0, __float_as_int(x),         \
                                            ctrl, rmask, 0xf, false);     \
        x += __int_as_float(o);                                           \
    }
    SSTEP(0x111, 0xf) SSTEP(0x112, 0xf) SSTEP(0x114, 0xf) SSTEP(0x118, 0xf)
    SSTEP(0x142, 0xa) SSTEP(0x143, 0xc)
#undef SSTEP
    return __int_as_float(__builtin_amdgcn_readlane(__float_as_int(x), 63));
}

// ---------------------------------------------------------------------------
// Kernel 1: cost matrix. 4 waves/block, one n per wave (verified R6).
// ---------------------------------------------------------------------------
__global__ __launch_bounds__(256) void cost_kernel(
    const float* __restrict__ logits,   // [B,N,128]
    const float* __restrict__ corners,  // [B,N,8,3]
    const int*   __restrict__ labels,   // [B,64]
    const float* __restrict__ boxes,    // [B,64,7]
    float*       __restrict__ C)        // [B,N,64]
{
    const int b = blockIdx.y;
    const int n = blockIdx.x * 4 + (threadIdx.x >> 6);
    const int t = threadIdx.x & 63;
    const long bn = (long)b * Nv + n;

    const float2 l2 = ((const float2*)(logits + bn * NCls))[t];
    const float* cp = corners + bn * 24;
    float cx = 0.f, cy = 0.f, cz = 0.f;
    if (t < 8) { cx = cp[3 * t]; cy = cp[3 * t + 1]; cz = cp[3 * t + 2]; }
    const int    lbl = labels[b * Mv + t];
    const float* bx  = boxes + ((long)b * Mv + t) * 7;
    const float bx0 = bx[0], bx1 = bx[1], bx2 = bx[2];

    float e0 = expf(l2.x), e1 = expf(l2.y);
    float s  = wave_sum_f32(e0 + e1);

    cx = wave_sum_f32(cx) * 0.125f;
    cy = wave_sum_f32(cy) * 0.125f;
    cz = wave_sum_f32(cz) * 0.125f;

    float p0 = __shfl(e0, lbl >> 1, 64);
    float p1 = __shfl(e1, lbl >> 1, 64);
    float pm = ((lbl & 1) ? p1 : p0) / s;

    float dx = cx - bx0, dy = cy - bx1, dz = cz - bx2;
    C[bn * Mv + t] = 5.0f * sqrtf(dx * dx + dy * dy + dz * dz) - pm;
}

// ---------------------------------------------------------------------------
// Kernel 2: LAPJV-style LSA. R6 verified structure RESTORED (update pass
// kept — it's free latency cover for the prefetch; split f32/u32 reduce).
// R7 lesson: only critical-path cycles count; the Delta-form removed covered
// work and exposed load latency (148->207us). R8 surgical cuts only:
//  1. v pre-folded into gather (crow = load - v): exact because v changes
//     only for used slots, which are BIGV-masked. Scan: cur = crow[k]-u_i0.
//     ((a-v)-u vs (a-u)-v reorder is ~ulp; R7's stronger reorder passed.)
//  2. 3-way split bestv chain (strict-< merges preserve first-j tie-break).
//  3. SELTREE15 p-lookup (depth 4, HW-verified R7).
// ---------------------------------------------------------------------------
__global__ __launch_bounds__(64) void lsa_kernel(
    const float* __restrict__ C,    // [B, N, M] = [64,900,64]
    float* __restrict__ outPred, float* __restrict__ outTgt)
{
    const int b = blockIdx.x;
    const int t = threadIdx.x;
    const float* cb = C + (size_t)b * Nv * Mv;

    // ---- Phase A: row argmin (lane t = row t+1); 4 ranges, deep unroll
    float mv0 = INFV, mv1 = INFV, mv2 = INFV, mv3 = INFV;
    int   mj0 = 0,    mj1 = 0,    mj2 = 0,    mj3 = 0;
    #pragma unroll 9
    for (int n = 0; n < 225; ++n) {
        float c0 = cb[(size_t)(n      ) * Mv + t];
        float c1 = cb[(size_t)(n + 225) * Mv + t];
        float c2 = cb[(size_t)(n + 450) * Mv + t];
        float c3 = cb[(size_t)(n + 675) * Mv + t];
        if (c0 < mv0) { mv0 = c0; mj0 = n;       }
        if (c1 < mv1) { mv1 = c1; mj1 = n + 225; }
        if (c2 < mv2) { mv2 = c2; mj2 = n + 450; }
        if (c3 < mv3) { mv3 = c3; mj3 = n + 675; }
    }
    float rowmin = mv0; int rown = mj0;
    if (mv1 < rowmin) { rowmin = mv1; rown = mj1; }
    if (mv2 < rowmin) { rowmin = mv2; rown = mj2; }
    if (mv3 < rowmin) { rowmin = mv3; rown = mj3; }

    float u_reg = rowmin;            // lane l holds u[l+1]
    const int jcol = rown + 1;       // column index in 1..900

    // ---- Phase B: duplicate detection (first occurrence wins)
    bool isdup = false;
    #pragma unroll
    for (int s = 1; s < 64; ++s) {
        int oj = __shfl(jcol, (t + 64 - s) & 63, 64);
        isdup |= (oj == jcol) && (s <= t);
    }
    unsigned long long pending = __ballot(isdup);

    int   p_reg[KREG], way_reg[KREG];
    float v_reg[KREG], minv[KREG], crow[KREG];
    #pragma unroll
    for (int k = 0; k < KREG; k++) { p_reg[k] = 0; way_reg[k] = 0; v_reg[k] = 0.f; }

    int rowcol = isdup ? 0 : jcol;   // lane i: column assigned to row i+1

    // scatter winners into distributed p[]
    #pragma unroll 8
    for (int i = 0; i < 64; ++i) {
        int jb = __shfl(jcol, i, 64);
        if (!((pending >> i) & 1ull) && t == (jb & 63))
            SET15(p_reg, jb >> 6, i + 1);
    }

    // ---- Phase C: Dijkstra phases for conflicted rows only
    while (pending) {
        const int i1v = __ffsll(pending);    // 1-based free row
        pending &= pending - 1;

        unsigned usedMask = (t == 0) ? 1u : 0u;   // dummy col 0 used
        unsigned long long rowMask = 0;
        #pragma unroll
        for (int k = 0; k < KREG; k++) minv[k] = INFV;

        int j0 = 0;
        int i0 = i1v;

        // initial gather for row i0 (v pre-folded; used/invalid -> BIGV)
        #pragma unroll
        for (int k = 0; k < KREG; k++) {
            int j = t + (k << 6);
            bool valid = (j >= 1 && j < NCOLS) && !((usedMask >> k) & 1u);
            crow[k] = valid
                      ? cb[(((size_t)(j - 1)) << 6) + (i0 - 1)] - v_reg[k] : BIGV;
        }

        while (true) {
            rowMask |= 1ull << (i0 - 1);
            const int sl = __builtin_amdgcn_readfirstlane(i0 - 1);
            const float u_i0 = __int_as_float(
                __builtin_amdgcn_readlane(__float_as_int(u_reg), sl));

            // scan (v pre-folded): 3-way split; strict-< merges keep first-j
            float bv0 = INFV, bv1 = INFV, bv2 = INFV;
            int   bk0 = 0,    bk1 = 5,    bk2 = 10;
            #pragma unroll
            for (int k = 0; k < 5; k++) {
                float cur = crow[k] - u_i0;
                if (cur < minv[k]) { minv[k] = cur; way_reg[k] = j0; }
                if (minv[k] < bv0) { bv0 = minv[k]; bk0 = k; }
            }
            #pragma unroll
            for (int k = 5; k < 10; k++) {
                float cur = crow[k] - u_i0;
                if (cur < minv[k]) { minv[k] = cur; way_reg[k] = j0; }
                if (minv[k] < bv1) { bv1 = minv[k]; bk1 = k; }
            }
            #pragma unroll
            for (int k = 10; k < KREG; k++) {
                float cur = crow[k] - u_i0;
                if (cur < minv[k]) { minv[k] = cur; way_reg[k] = j0; }
                if (minv[k] < bv2) { bv2 = minv[k]; bk2 = k; }
            }
            if (bv1 < bv0) { bv0 = bv1; bk0 = bk1; }
            if (bv2 < bv0) { bv0 = bv2; bk0 = bk2; }

            // delta: fast f32 min chain (exact min)
            const float delta = wave_min_f32(bv0);

            // argmin j (first index attaining min), overlaps update loop
            unsigned jc = (bv0 == delta)
                          ? (unsigned)(t + (bk0 << 6)) : 0xFFFFFFFFu;
            const int j1 = (int)wave_min_u32(jc);

            const int k1 = j1 >> 6, l1 = j1 & 63;   // uniform (SGPR)
            int ptmp; SELTREE15(p_reg, k1, ptmp);
            const int inext = __builtin_amdgcn_readlane(ptmp, l1);

            // prefetch next row (mask + v fold inline); latency hides under
            // the update pass below (R6-verified cover)
            const bool newbit = (t == l1);
            unsigned newUsed = usedMask | (newbit ? (1u << k1) : 0u);
            if (inext != 0) {
                const int src = inext - 1;
                #pragma unroll
                for (int k = 0; k < KREG; k++) {
                    int j = t + (k << 6);
                    bool valid = (j >= 1 && j < NCOLS) && !((newUsed >> k) & 1u);
                    crow[k] = valid
                              ? cb[(((size_t)(j - 1)) << 6) + src] - v_reg[k] : BIGV;
                }
            }

            // dual/distance updates (reference order: used = OLD usedMask;
            // newly-selected slot gets minv=INFV = reference's INF mask)
            if ((rowMask >> t) & 1ull) u_reg += delta;
            #pragma unroll
            for (int k = 0; k < KREG; k++) {
                bool used  = (usedMask >> k) & 1u;
                bool isnew = newbit && (k == k1);
                v_reg[k] = used ? v_reg[k] - delta : v_reg[k];
                float mupd = used ? minv[k] : minv[k] - delta;
                minv[k] = isnew ? INFV : mupd;
            }
            usedMask = newUsed;

            j0 = j1;
            i0 = inext;
            if (i0 == 0) break;              // free column reached
        }

        // backtrack: reassign columns along augmenting path
        while (j0 != 0) {
            const int k0 = j0 >> 6, l0 = j0 & 63;
            int wtmp; SEL15(way_reg, k0, wtmp);
            const int jprev = __shfl(wtmp, l0, 64);
            int pv;
            if (jprev == 0) {
                pv = i1v;
            } else {
                int ptmp2; SEL15(p_reg, jprev >> 6, ptmp2);
                pv = __shfl(ptmp2, jprev & 63, 64);
            }
            if (t == l0) SET15(p_reg, k0, pv);
            if (t == pv - 1) rowcol = j0;    // maintain row->column mirror
            j0 = jprev;
        }
    }

    outPred[b * Mv + t] = (float)(rowcol - 1);
    outTgt[b * Mv + t]  = (float)t;
}

// ---------------------------------------------------------------------------
extern "C" void kernel_launch(void* const* d_in, const int* in_sizes, int n_in,
                              void* d_out, int out_size, void* d_ws, size_t ws_size,
                              hipStream_t stream)
{
    (void)in_sizes; (void)n_in; (void)out_size; (void)d_ws; (void)ws_size;

    const float* logits  = (const float*)d_in[0];   // [64,900,128] f32
    const float* corners = (const float*)d_in[1];   // [64,900,8,3] f32
    const int*   labels  = (const int*)  d_in[2];   // [64,64] i32
    const float* boxes   = (const float*)d_in[3];   // [64,64,7] f32

    float* out  = (float*)d_out;
    float* Cc   = out;                               // [64,900,64]
    float* pred = out + (size_t)Bv * Nv * Mv;        // [64,64] as f32
    float* tgt  = pred + (size_t)Bv * Mv;            // [64,64] as f32

    cost_kernel<<<dim3(225, Bv), 256, 0, stream>>>(logits, corners, labels, boxes, Cc);
    lsa_kernel<<<Bv, 64, 0, stream>>>(Cc, pred, tgt);
}

// Round 9
// 236.986 us; speedup vs baseline: 1.5363x; 1.5363x over previous
//
#include <hip/hip_runtime.h>
#include <math.h>

#define Bv   64
#define Nv   900
#define Mv   64
#define NCls 128
#define NCOLS (Nv + 1)          // 901 columns incl. dummy col 0
#define KREG 15                 // columns per lane: j = t + 64k, k=0..14
#define INFV 1000000000.0f
#define BIGV 1.0e18f            // sentinel for used/invalid slots

// uniform dynamic read (serial chain; only in the rare backtrack)
#define SEL15(arr, kidx, dst) do {            \
    int _s = arr[0];                          \
    _Pragma("unroll")                         \
    for (int _kk = 1; _kk < KREG; _kk++)      \
        _s = ((kidx) == _kk) ? arr[_kk] : _s; \
    (dst) = _s;                               \
} while (0)

// binary-tree select (depth 4) for the hot p-lookup; kidx uniform.
// HW-verified R7/R8.
#define SELTREE15(arr, kidx, dst) do {                      \
    int _a0 = ((kidx) & 1) ? arr[1]  : arr[0];              \
    int _a1 = ((kidx) & 1) ? arr[3]  : arr[2];              \
    int _a2 = ((kidx) & 1) ? arr[5]  : arr[4];              \
    int _a3 = ((kidx) & 1) ? arr[7]  : arr[6];              \
    int _a4 = ((kidx) & 1) ? arr[9]  : arr[8];              \
    int _a5 = ((kidx) & 1) ? arr[11] : arr[10];             \
    int _a6 = ((kidx) & 1) ? arr[13] : arr[12];             \
    int _a7 = arr[14];          /* k==15 never occurs */    \
    int _b0 = ((kidx) & 2) ? _a1 : _a0;                     \
    int _b1 = ((kidx) & 2) ? _a3 : _a2;                     \
    int _b2 = ((kidx) & 2) ? _a5 : _a4;                     \
    int _b3 = ((kidx) & 2) ? _a7 : _a6;                     \
    int _c0 = ((kidx) & 4) ? _b1 : _b0;                     \
    int _c1 = ((kidx) & 4) ? _b3 : _b2;                     \
    (dst)   = ((kidx) & 8) ? _c1 : _c0;                     \
} while (0)

// uniform dynamic write (lane-targeted)
#define SET15(arr, kidx, val) do {            \
    _Pragma("unroll")                         \
    for (int _kk = 0; _kk < KREG; _kk++)      \
        if ((kidx) == _kk) arr[_kk] = (val);  \
} while (0)

// ---- wave64 reduces via DPP (rocPRIM pattern, HW-verified R4-R8) -----------
__device__ __forceinline__ float wave_min_f32(float x) {
#define MSTEP(ctrl, rmask)                                                \
    {                                                                     \
        int o = __builtin_amdgcn_update_dpp(__float_as_int(x),            \
                __float_as_int(x), ctrl, rmask, 0xf, false);              \
        x = fminf(x, __int_as_float(o));                                  \
    }
    MSTEP(0x111, 0xf) MSTEP(0x112, 0xf) MSTEP(0x114, 0xf) MSTEP(0x118, 0xf)
    MSTEP(0x142, 0xa) MSTEP(0x143, 0xc)
#undef MSTEP
    return __int_as_float(__builtin_amdgcn_readlane(__float_as_int(x), 63));
}

__device__ __forceinline__ unsigned wave_min_u32(unsigned x) {
#define USTEP(ctrl, rmask)                                                \
    {                                                                     \
        unsigned o = (unsigned)__builtin_amdgcn_update_dpp((int)x,        \
                     (int)x, ctrl, rmask, 0xf, false);                    \
        x = (o < x) ? o : x;                                              \
    }
    USTEP(0x111, 0xf) USTEP(0x112, 0xf) USTEP(0x114, 0xf) USTEP(0x118, 0xf)
    USTEP(0x142, 0xa) USTEP(0x143, 0xc)
#undef USTEP
    return (unsigned)__builtin_amdgcn_readlane((int)x, 63);
}

__device__ __forceinline__ float wave_sum_f32(float x) {
#define SSTEP(ctrl, rmask)                                                \
    {                                                                     \
        int o = __builtin_amdgcn_update_dpp(0, __float_as_int(x),         \
                                            ctrl, rmask, 0xf, false);     \
        x += __int_as_float(o);                                           \
    }
    SSTEP(0x111, 0xf) SSTEP(0x112, 0xf) SSTEP(0x114, 0xf) SSTEP(0x118, 0xf)
    SSTEP(0x142, 0xa) SSTEP(0x143, 0xc)
#undef SSTEP
    return __int_as_float(__builtin_amdgcn_readlane(__float_as_int(x), 63));
}

// ---------------------------------------------------------------------------
// Kernel 1: cost matrix. 4 waves/block, one n per wave (verified R6).
// ---------------------------------------------------------------------------
__global__ __launch_bounds__(256) void cost_kernel(
    const float* __restrict__ logits,   // [B,N,128]
    const float* __restrict__ corners,  // [B,N,8,3]
    const int*   __restrict__ labels,   // [B,64]
    const float* __restrict__ boxes,    // [B,64,7]
    float*       __restrict__ C)        // [B,N,64]
{
    const int b = blockIdx.y;
    const int n = blockIdx.x * 4 + (threadIdx.x >> 6);
    const int t = threadIdx.x & 63;
    const long bn = (long)b * Nv + n;

    const float2 l2 = ((const float2*)(logits + bn * NCls))[t];
    const float* cp = corners + bn * 24;
    float cx = 0.f, cy = 0.f, cz = 0.f;
    if (t < 8) { cx = cp[3 * t]; cy = cp[3 * t + 1]; cz = cp[3 * t + 2]; }
    const int    lbl = labels[b * Mv + t];
    const float* bx  = boxes + ((long)b * Mv + t) * 7;
    const float bx0 = bx[0], bx1 = bx[1], bx2 = bx[2];

    float e0 = expf(l2.x), e1 = expf(l2.y);
    float s  = wave_sum_f32(e0 + e1);

    cx = wave_sum_f32(cx) * 0.125f;
    cy = wave_sum_f32(cy) * 0.125f;
    cz = wave_sum_f32(cz) * 0.125f;

    float p0 = __shfl(e0, lbl >> 1, 64);
    float p1 = __shfl(e1, lbl >> 1, 64);
    float pm = ((lbl & 1) ? p1 : p0) / s;

    float dx = cx - bx0, dy = cy - bx1, dz = cz - bx2;
    C[bn * Mv + t] = 5.0f * sqrtf(dx * dx + dy * dy + dz * dz) - pm;
}

// ---------------------------------------------------------------------------
// Kernel 2: LAPJV-style LSA. EXACT R6 structure (148us verified):
//   - prefetch holds the RAW load (no arithmetic folded!) so the compiler
//     sinks the vmcnt wait across the backedge into the next scan; the
//     update pass + reduce run UNDER the gather latency. R7 (Delta-form)
//     and R8 (v-fold at prefetch) both broke this cover and regressed
//     (148 -> 207 / 280us). Do not compute anything from loaded values
//     before the update pass.
//   - scan: cur = (crow[k] - u_i0) - v_reg[k]; sentinel masking (BIGV/INFV)
//     keeps the scan free of used-tests (R6-verified exact).
// R9 adds ONLY the R8-hardware-verified pure-VALU cuts (off the load path):
//   1. 3-way split bestv chains, strict-< merges (exact first-j tie-break).
//   2. SELTREE15 p-lookup (depth 4 vs 14).
// ---------------------------------------------------------------------------
__global__ __launch_bounds__(64) void lsa_kernel(
    const float* __restrict__ C,    // [B, N, M] = [64,900,64]
    float* __restrict__ outPred, float* __restrict__ outTgt)
{
    const int b = blockIdx.x;
    const int t = threadIdx.x;
    const float* cb = C + (size_t)b * Nv * Mv;

    // ---- Phase A: row argmin (lane t = row t+1); 4 ranges, deep unroll
    float mv0 = INFV, mv1 = INFV, mv2 = INFV, mv3 = INFV;
    int   mj0 = 0,    mj1 = 0,    mj2 = 0,    mj3 = 0;
    #pragma unroll 9
    for (int n = 0; n < 225; ++n) {
        float c0 = cb[(size_t)(n      ) * Mv + t];
        float c1 = cb[(size_t)(n + 225) * Mv + t];
        float c2 = cb[(size_t)(n + 450) * Mv + t];
        float c3 = cb[(size_t)(n + 675) * Mv + t];
        if (c0 < mv0) { mv0 = c0; mj0 = n;       }
        if (c1 < mv1) { mv1 = c1; mj1 = n + 225; }
        if (c2 < mv2) { mv2 = c2; mj2 = n + 450; }
        if (c3 < mv3) { mv3 = c3; mj3 = n + 675; }
    }
    float rowmin = mv0; int rown = mj0;
    if (mv1 < rowmin) { rowmin = mv1; rown = mj1; }
    if (mv2 < rowmin) { rowmin = mv2; rown = mj2; }
    if (mv3 < rowmin) { rowmin = mv3; rown = mj3; }

    float u_reg = rowmin;            // lane l holds u[l+1]
    const int jcol = rown + 1;       // column index in 1..900

    // ---- Phase B: duplicate detection (first occurrence wins)
    bool isdup = false;
    #pragma unroll
    for (int s = 1; s < 64; ++s) {
        int oj = __shfl(jcol, (t + 64 - s) & 63, 64);
        isdup |= (oj == jcol) && (s <= t);
    }
    unsigned long long pending = __ballot(isdup);

    int   p_reg[KREG], way_reg[KREG];
    float v_reg[KREG], minv[KREG], crow[KREG];
    #pragma unroll
    for (int k = 0; k < KREG; k++) { p_reg[k] = 0; way_reg[k] = 0; v_reg[k] = 0.f; }

    int rowcol = isdup ? 0 : jcol;   // lane i: column assigned to row i+1

    // scatter winners into distributed p[]
    #pragma unroll 8
    for (int i = 0; i < 64; ++i) {
        int jb = __shfl(jcol, i, 64);
        if (!((pending >> i) & 1ull) && t == (jb & 63))
            SET15(p_reg, jb >> 6, i + 1);
    }

    // ---- Phase C: Dijkstra phases for conflicted rows only
    while (pending) {
        const int i1v = __ffsll(pending);    // 1-based free row
        pending &= pending - 1;

        unsigned usedMask = (t == 0) ? 1u : 0u;   // dummy col 0 used
        unsigned long long rowMask = 0;
        #pragma unroll
        for (int k = 0; k < KREG; k++) minv[k] = INFV;

        int j0 = 0;
        int i0 = i1v;

        // initial gather for row i0; j==0 and j>=NCOLS slots get BIGV
        #pragma unroll
        for (int k = 0; k < KREG; k++) {
            int j = t + (k << 6);
            crow[k] = (j >= 1 && j < NCOLS)
                      ? cb[(((size_t)(j - 1)) << 6) + (i0 - 1)] : BIGV;
        }

        while (true) {
            rowMask |= 1ull << (i0 - 1);
            const int sl = __builtin_amdgcn_readfirstlane(i0 - 1);
            const float u_i0 = __int_as_float(
                __builtin_amdgcn_readlane(__float_as_int(u_reg), sl));

            // scan: used/invalid slots carry crow=BIGV & minv=INFV -> no
            // per-slot used test (R6-verified). 3-way split chains; strict-<
            // merges keep exact first-j tie-break (R8-verified).
            float bv0 = INFV, bv1 = INFV, bv2 = INFV;
            int   bk0 = 0,    bk1 = 5,    bk2 = 10;
            #pragma unroll
            for (int k = 0; k < 5; k++) {
                float cur = (crow[k] - u_i0) - v_reg[k];
                if (cur < minv[k]) { minv[k] = cur; way_reg[k] = j0; }
                if (minv[k] < bv0) { bv0 = minv[k]; bk0 = k; }
            }
            #pragma unroll
            for (int k = 5; k < 10; k++) {
                float cur = (crow[k] - u_i0) - v_reg[k];
                if (cur < minv[k]) { minv[k] = cur; way_reg[k] = j0; }
                if (minv[k] < bv1) { bv1 = minv[k]; bk1 = k; }
            }
            #pragma unroll
            for (int k = 10; k < KREG; k++) {
                float cur = (crow[k] - u_i0) - v_reg[k];
                if (cur < minv[k]) { minv[k] = cur; way_reg[k] = j0; }
                if (minv[k] < bv2) { bv2 = minv[k]; bk2 = k; }
            }
            if (bv1 < bv0) { bv0 = bv1; bk0 = bk1; }
            if (bv2 < bv0) { bv0 = bv2; bk0 = bk2; }

            // delta: fast f32 min chain (exact min)
            const float delta = wave_min_f32(bv0);

            // argmin j (first index attaining min), overlaps update loop
            unsigned jc = (bv0 == delta)
                          ? (unsigned)(t + (bk0 << 6)) : 0xFFFFFFFFu;
            const int j1 = (int)wave_min_u32(jc);

            const int k1 = j1 >> 6, l1 = j1 & 63;   // uniform (SGPR)
            int ptmp; SELTREE15(p_reg, k1, ptmp);
            const int inext = __builtin_amdgcn_readlane(ptmp, l1);

            // prefetch next row: RAW loads only (masked by newUsed via
            // cndmask on the address-valid path, value untouched) — the
            // vmcnt wait sinks into the NEXT scan, covered by the update
            // pass below. Do NOT fold arithmetic here (R7/R8 lesson).
            const bool newbit = (t == l1);
            unsigned newUsed = usedMask | (newbit ? (1u << k1) : 0u);
            if (inext != 0) {
                const int src = inext - 1;
                #pragma unroll
                for (int k = 0; k < KREG; k++) {
                    int j = t + (k << 6);
                    bool valid = (j >= 1 && j < NCOLS) && !((newUsed >> k) & 1u);
                    crow[k] = valid
                              ? cb[(((size_t)(j - 1)) << 6) + src] : BIGV;
                }
            }

            // dual/distance updates (reference order: used = OLD usedMask;
            // newly-selected slot gets minv=INFV = reference's INF mask).
            // This pass is the latency cover for the prefetch above.
            if ((rowMask >> t) & 1ull) u_reg += delta;
            #pragma unroll
            for (int k = 0; k < KREG; k++) {
                bool used  = (usedMask >> k) & 1u;
                bool isnew = newbit && (k == k1);
                v_reg[k] = used ? v_reg[k] - delta : v_reg[k];
                float mupd = used ? minv[k] : minv[k] - delta;
                minv[k] = isnew ? INFV : mupd;
            }
            usedMask = newUsed;

            j0 = j1;
            i0 = inext;
            if (i0 == 0) break;              // free column reached
        }

        // backtrack: reassign columns along augmenting path
        while (j0 != 0) {
            const int k0 = j0 >> 6, l0 = j0 & 63;
            int wtmp; SEL15(way_reg, k0, wtmp);
            const int jprev = __shfl(wtmp, l0, 64);
            int pv;
            if (jprev == 0) {
                pv = i1v;
            } else {
                int ptmp2; SEL15(p_reg, jprev >> 6, ptmp2);
                pv = __shfl(ptmp2, jprev & 63, 64);
            }
            if (t == l0) SET15(p_reg, k0, pv);
            if (t == pv - 1) rowcol = j0;    // maintain row->column mirror
            j0 = jprev;
        }
    }

    outPred[b * Mv + t] = (float)(rowcol - 1);
    outTgt[b * Mv + t]  = (float)t;
}

// ---------------------------------------------------------------------------
extern "C" void kernel_launch(void* const* d_in, const int* in_sizes, int n_in,
                              void* d_out, int out_size, void* d_ws, size_t ws_size,
                              hipStream_t stream)
{
    (void)in_sizes; (void)n_in; (void)out_size; (void)d_ws; (void)ws_size;

    const float* logits  = (const float*)d_in[0];   // [64,900,128] f32
    const float* corners = (const float*)d_in[1];   // [64,900,8,3] f32
    const int*   labels  = (const int*)  d_in[2];   // [64,64] i32
    const float* boxes   = (const float*)d_in[3];   // [64,64,7] f32

    float* out  = (float*)d_out;
    float* Cc   = out;                               // [64,900,64]
    float* pred = out + (size_t)Bv * Nv * Mv;        // [64,64] as f32
    float* tgt  = pred + (size_t)Bv * Mv;            // [64,64] as f32

    cost_kernel<<<dim3(225, Bv), 256, 0, stream>>>(logits, corners, labels, boxes, Cc);
    lsa_kernel<<<Bv, 64, 0, stream>>>(Cc, pred, tgt);
}

// Round 10
// 236.507 us; speedup vs baseline: 1.5394x; 1.0020x over previous
//
#include <hip/hip_runtime.h>
#include <math.h>

#define Bv   64
#define Nv   900
#define Mv   64
#define NCls 128
#define NCOLS (Nv + 1)          // 901 columns incl. dummy col 0
#define KREG 15                 // columns per lane: j = t + 64k, k=0..14
#define INFV 1000000000.0f
#define BIGV 1.0e18f            // sentinel for used/invalid slots

// uniform dynamic read (serial chain; only in the rare backtrack)
#define SEL15(arr, kidx, dst) do {            \
    int _s = arr[0];                          \
    _Pragma("unroll")                         \
    for (int _kk = 1; _kk < KREG; _kk++)      \
        _s = ((kidx) == _kk) ? arr[_kk] : _s; \
    (dst) = _s;                               \
} while (0)

// binary-tree select (depth 4). kidx may be PER-LANE (compiles to cndmask
// tree). HW-verified R7/R8/R9.
#define SELTREE15(arr, kidx, dst) do {                      \
    int _a0 = ((kidx) & 1) ? arr[1]  : arr[0];              \
    int _a1 = ((kidx) & 1) ? arr[3]  : arr[2];              \
    int _a2 = ((kidx) & 1) ? arr[5]  : arr[4];              \
    int _a3 = ((kidx) & 1) ? arr[7]  : arr[6];              \
    int _a4 = ((kidx) & 1) ? arr[9]  : arr[8];              \
    int _a5 = ((kidx) & 1) ? arr[11] : arr[10];             \
    int _a6 = ((kidx) & 1) ? arr[13] : arr[12];             \
    int _a7 = arr[14];          /* k==15 never occurs */    \
    int _b0 = ((kidx) & 2) ? _a1 : _a0;                     \
    int _b1 = ((kidx) & 2) ? _a3 : _a2;                     \
    int _b2 = ((kidx) & 2) ? _a5 : _a4;                     \
    int _b3 = ((kidx) & 2) ? _a7 : _a6;                     \
    int _c0 = ((kidx) & 4) ? _b1 : _b0;                     \
    int _c1 = ((kidx) & 4) ? _b3 : _b2;                     \
    (dst)   = ((kidx) & 8) ? _c1 : _c0;                     \
} while (0)

// uniform dynamic write (lane-targeted)
#define SET15(arr, kidx, val) do {            \
    _Pragma("unroll")                         \
    for (int _kk = 0; _kk < KREG; _kk++)      \
        if ((kidx) == _kk) arr[_kk] = (val);  \
} while (0)

// ---- order-preserving float <-> sortable u32 (bit-exact round trip) --------
__device__ __forceinline__ unsigned f2s(float f) {
    unsigned x = __float_as_uint(f);
    return x ^ ((unsigned)((int)x >> 31) | 0x80000000u);
}
__device__ __forceinline__ float s2f(unsigned s) {
    unsigned x = ((int)s < 0) ? (s ^ 0x80000000u) : ~s;
    return __uint_as_float(x);
}

// ---- wave64 min-reduce of packed (hi=sortable value, lo) via DPP -----------
// HW-verified R4/R7. Lexicographic (value, lo); with lo = (j<<7)|p[j] this
// gives first-j tie-break (p is a function of j, so it never affects order).
__device__ __forceinline__ void wave_min_pair(unsigned& hi, unsigned& lo) {
#define DPP_STEP(ctrl, rmask)                                                   \
    {                                                                           \
        unsigned ohi = (unsigned)__builtin_amdgcn_update_dpp(                   \
            (int)hi, (int)hi, ctrl, rmask, 0xf, false);                         \
        unsigned olo = (unsigned)__builtin_amdgcn_update_dpp(                   \
            (int)lo, (int)lo, ctrl, rmask, 0xf, false);                         \
        bool take = (ohi < hi) || (ohi == hi && olo < lo);                      \
        hi = take ? ohi : hi;                                                   \
        lo = take ? olo : lo;                                                   \
    }
    DPP_STEP(0x111, 0xf)   // row_shr:1
    DPP_STEP(0x112, 0xf)   // row_shr:2
    DPP_STEP(0x114, 0xf)   // row_shr:4
    DPP_STEP(0x118, 0xf)   // row_shr:8
    DPP_STEP(0x142, 0xa)   // row_bcast:15
    DPP_STEP(0x143, 0xc)   // row_bcast:31 -> lane 63 holds min
#undef DPP_STEP
    hi = (unsigned)__builtin_amdgcn_readlane((int)hi, 63);
    lo = (unsigned)__builtin_amdgcn_readlane((int)lo, 63);
}

__device__ __forceinline__ float wave_sum_f32(float x) {
#define SSTEP(ctrl, rmask)                                                \
    {                                                                     \
        int o = __builtin_amdgcn_update_dpp(0, __float_as_int(x),         \
                                            ctrl, rmask, 0xf, false);     \
        x += __int_as_float(o);                                           \
    }
    SSTEP(0x111, 0xf) SSTEP(0x112, 0xf) SSTEP(0x114, 0xf) SSTEP(0x118, 0xf)
    SSTEP(0x142, 0xa) SSTEP(0x143, 0xc)
#undef SSTEP
    return __int_as_float(__builtin_amdgcn_readlane(__float_as_int(x), 63));
}

// ---------------------------------------------------------------------------
// Kernel 1: cost matrix. 4 waves/block, one n per wave (verified R6).
// ---------------------------------------------------------------------------
__global__ __launch_bounds__(256) void cost_kernel(
    const float* __restrict__ logits,   // [B,N,128]
    const float* __restrict__ corners,  // [B,N,8,3]
    const int*   __restrict__ labels,   // [B,64]
    const float* __restrict__ boxes,    // [B,64,7]
    float*       __restrict__ C)        // [B,N,64]
{
    const int b = blockIdx.y;
    const int n = blockIdx.x * 4 + (threadIdx.x >> 6);
    const int t = threadIdx.x & 63;
    const long bn = (long)b * Nv + n;

    const float2 l2 = ((const float2*)(logits + bn * NCls))[t];
    const float* cp = corners + bn * 24;
    float cx = 0.f, cy = 0.f, cz = 0.f;
    if (t < 8) { cx = cp[3 * t]; cy = cp[3 * t + 1]; cz = cp[3 * t + 2]; }
    const int    lbl = labels[b * Mv + t];
    const float* bx  = boxes + ((long)b * Mv + t) * 7;
    const float bx0 = bx[0], bx1 = bx[1], bx2 = bx[2];

    float e0 = expf(l2.x), e1 = expf(l2.y);
    float s  = wave_sum_f32(e0 + e1);

    cx = wave_sum_f32(cx) * 0.125f;
    cy = wave_sum_f32(cy) * 0.125f;
    cz = wave_sum_f32(cz) * 0.125f;

    float p0 = __shfl(e0, lbl >> 1, 64);
    float p1 = __shfl(e1, lbl >> 1, 64);
    float pm = ((lbl & 1) ? p1 : p0) / s;

    float dx = cx - bx0, dy = cy - bx1, dz = cz - bx2;
    C[bn * Mv + t] = 5.0f * sqrtf(dx * dx + dy * dy + dz * dz) - pm;
}

// ---------------------------------------------------------------------------
// Kernel 2: LAPJV-style LSA. R6/R9 verified structure (raw prefetch, update
// pass as latency cover, sentinel masking, split scan chains).
// R10: FUSED packed reduce — per-lane p-candidate (each lane's best-j p value
// lives in its OWN p_reg[bk0]) packed as lo=(j<<7)|p, hi=f2s(bv0); one
// wave_min_pair yields delta, j1 AND inext simultaneously. Removes the serial
// delta->argmin-chain->SELTREE->readlane segment (~110cy) from the path to
// the next row's load issue. R9 showed the scan has slack; the reduce chain
// and load issue ARE the path.
// ---------------------------------------------------------------------------
__global__ __launch_bounds__(64) void lsa_kernel(
    const float* __restrict__ C,    // [B, N, M] = [64,900,64]
    float* __restrict__ outPred, float* __restrict__ outTgt)
{
    const int b = blockIdx.x;
    const int t = threadIdx.x;
    const float* cb = C + (size_t)b * Nv * Mv;

    // ---- Phase A: row argmin (lane t = row t+1); 4 ranges, deep unroll
    float mv0 = INFV, mv1 = INFV, mv2 = INFV, mv3 = INFV;
    int   mj0 = 0,    mj1 = 0,    mj2 = 0,    mj3 = 0;
    #pragma unroll 9
    for (int n = 0; n < 225; ++n) {
        float c0 = cb[(size_t)(n      ) * Mv + t];
        float c1 = cb[(size_t)(n + 225) * Mv + t];
        float c2 = cb[(size_t)(n + 450) * Mv + t];
        float c3 = cb[(size_t)(n + 675) * Mv + t];
        if (c0 < mv0) { mv0 = c0; mj0 = n;       }
        if (c1 < mv1) { mv1 = c1; mj1 = n + 225; }
        if (c2 < mv2) { mv2 = c2; mj2 = n + 450; }
        if (c3 < mv3) { mv3 = c3; mj3 = n + 675; }
    }
    float rowmin = mv0; int rown = mj0;
    if (mv1 < rowmin) { rowmin = mv1; rown = mj1; }
    if (mv2 < rowmin) { rowmin = mv2; rown = mj2; }
    if (mv3 < rowmin) { rowmin = mv3; rown = mj3; }

    float u_reg = rowmin;            // lane l holds u[l+1]
    const int jcol = rown + 1;       // column index in 1..900

    // ---- Phase B: duplicate detection (first occurrence wins)
    bool isdup = false;
    #pragma unroll
    for (int s = 1; s < 64; ++s) {
        int oj = __shfl(jcol, (t + 64 - s) & 63, 64);
        isdup |= (oj == jcol) && (s <= t);
    }
    unsigned long long pending = __ballot(isdup);

    int   p_reg[KREG], way_reg[KREG];
    float v_reg[KREG], minv[KREG], crow[KREG];
    #pragma unroll
    for (int k = 0; k < KREG; k++) { p_reg[k] = 0; way_reg[k] = 0; v_reg[k] = 0.f; }

    int rowcol = isdup ? 0 : jcol;   // lane i: column assigned to row i+1

    // scatter winners into distributed p[]
    #pragma unroll 8
    for (int i = 0; i < 64; ++i) {
        int jb = __shfl(jcol, i, 64);
        if (!((pending >> i) & 1ull) && t == (jb & 63))
            SET15(p_reg, jb >> 6, i + 1);
    }

    // ---- Phase C: Dijkstra phases for conflicted rows only
    while (pending) {
        const int i1v = __ffsll(pending);    // 1-based free row
        pending &= pending - 1;

        unsigned usedMask = (t == 0) ? 1u : 0u;   // dummy col 0 used
        unsigned long long rowMask = 0;
        #pragma unroll
        for (int k = 0; k < KREG; k++) minv[k] = INFV;

        int j0 = 0;
        int i0 = i1v;

        // initial gather for row i0; j==0 and j>=NCOLS slots get BIGV
        #pragma unroll
        for (int k = 0; k < KREG; k++) {
            int j = t + (k << 6);
            crow[k] = (j >= 1 && j < NCOLS)
                      ? cb[(((size_t)(j - 1)) << 6) + (i0 - 1)] : BIGV;
        }

        while (true) {
            rowMask |= 1ull << (i0 - 1);
            const int sl = __builtin_amdgcn_readfirstlane(i0 - 1);
            const float u_i0 = __int_as_float(
                __builtin_amdgcn_readlane(__float_as_int(u_reg), sl));

            // scan: sentinel-masked (R6-verified), 3-way split (R8-verified)
            float bv0 = INFV, bv1 = INFV, bv2 = INFV;
            int   bk0 = 0,    bk1 = 5,    bk2 = 10;
            #pragma unroll
            for (int k = 0; k < 5; k++) {
                float cur = (crow[k] - u_i0) - v_reg[k];
                if (cur < minv[k]) { minv[k] = cur; way_reg[k] = j0; }
                if (minv[k] < bv0) { bv0 = minv[k]; bk0 = k; }
            }
            #pragma unroll
            for (int k = 5; k < 10; k++) {
                float cur = (crow[k] - u_i0) - v_reg[k];
                if (cur < minv[k]) { minv[k] = cur; way_reg[k] = j0; }
                if (minv[k] < bv1) { bv1 = minv[k]; bk1 = k; }
            }
            #pragma unroll
            for (int k = 10; k < KREG; k++) {
                float cur = (crow[k] - u_i0) - v_reg[k];
                if (cur < minv[k]) { minv[k] = cur; way_reg[k] = j0; }
                if (minv[k] < bv2) { bv2 = minv[k]; bk2 = k; }
            }
            if (bv1 < bv0) { bv0 = bv1; bk0 = bk1; }
            if (bv2 < bv0) { bv0 = bv2; bk0 = bk2; }

            // per-lane p-candidate: this lane's best j = t + (bk0<<6), whose
            // p value is this lane's OWN p_reg[bk0] (parallel depth-4 tree)
            int pcand; SELTREE15(p_reg, bk0, pcand);

            // fused reduce: (value, j, p[j]) -> delta + j1 + inext at once.
            // lo=(j<<7)|p: j<=959 (10b), p<=64 (7b); order = (value, j).
            unsigned hi = f2s(bv0);
            unsigned lo = ((unsigned)(t + (bk0 << 6)) << 7) | (unsigned)pcand;
            wave_min_pair(hi, lo);
            const float delta = s2f(hi);
            const int   j1    = (int)(lo >> 7);
            const int   inext = (int)(lo & 0x7fu);

            const int k1 = j1 >> 6, l1 = j1 & 63;   // uniform (SGPR)

            // prefetch next row: RAW loads only (R7/R8 lesson: no arithmetic
            // on loaded values before the update pass) — vmcnt sinks into the
            // next scan, covered by the update pass below.
            const bool newbit = (t == l1);
            unsigned newUsed = usedMask | (newbit ? (1u << k1) : 0u);
            if (inext != 0) {
                const int src = inext - 1;
                #pragma unroll
                for (int k = 0; k < KREG; k++) {
                    int j = t + (k << 6);
                    bool valid = (j >= 1 && j < NCOLS) && !((newUsed >> k) & 1u);
                    crow[k] = valid
                              ? cb[(((size_t)(j - 1)) << 6) + src] : BIGV;
                }
            }

            // dual/distance updates (reference order: used = OLD usedMask;
            // newly-selected slot gets minv=INFV = reference's INF mask).
            // This pass is the latency cover for the prefetch above.
            if ((rowMask >> t) & 1ull) u_reg += delta;
            #pragma unroll
            for (int k = 0; k < KREG; k++) {
                bool used  = (usedMask >> k) & 1u;
                bool isnew = newbit && (k == k1);
                v_reg[k] = used ? v_reg[k] - delta : v_reg[k];
                float mupd = used ? minv[k] : minv[k] - delta;
                minv[k] = isnew ? INFV : mupd;
            }
            usedMask = newUsed;

            j0 = j1;
            i0 = inext;
            if (i0 == 0) break;              // free column reached
        }

        // backtrack: reassign columns along augmenting path
        while (j0 != 0) {
            const int k0 = j0 >> 6, l0 = j0 & 63;
            int wtmp; SEL15(way_reg, k0, wtmp);
            const int jprev = __shfl(wtmp, l0, 64);
            int pv;
            if (jprev == 0) {
                pv = i1v;
            } else {
                int ptmp2; SEL15(p_reg, jprev >> 6, ptmp2);
                pv = __shfl(ptmp2, jprev & 63, 64);
            }
            if (t == l0) SET15(p_reg, k0, pv);
            if (t == pv - 1) rowcol = j0;    // maintain row->column mirror
            j0 = jprev;
        }
    }

    outPred[b * Mv + t] = (float)(rowcol - 1);
    outTgt[b * Mv + t]  = (float)t;
}

// ---------------------------------------------------------------------------
extern "C" void kernel_launch(void* const* d_in, const int* in_sizes, int n_in,
                              void* d_out, int out_size, void* d_ws, size_t ws_size,
                              hipStream_t stream)
{
    (void)in_sizes; (void)n_in; (void)out_size; (void)d_ws; (void)ws_size;

    const float* logits  = (const float*)d_in[0];   // [64,900,128] f32
    const float* corners = (const float*)d_in[1];   // [64,900,8,3] f32
    const int*   labels  = (const int*)  d_in[2];   // [64,64] i32
    const float* boxes   = (const float*)d_in[3];   // [64,64,7] f32

    float* out  = (float*)d_out;
    float* Cc   = out;                               // [64,900,64]
    float* pred = out + (size_t)Bv * Nv * Mv;        // [64,64] as f32
    float* tgt  = pred + (size_t)Bv * Mv;            // [64,64] as f32

    cost_kernel<<<dim3(225, Bv), 256, 0, stream>>>(logits, corners, labels, boxes, Cc);
    lsa_kernel<<<Bv, 64, 0, stream>>>(Cc, pred, tgt);
}